// Round 2
// baseline (233.257 us; speedup 1.0000x reference)
//
#include <hip/hip_runtime.h>
#include <hip/hip_bf16.h>

// MHA forward, bf16-MFMA pipeline.
// Shapes: B=2, L=P=2048, D=1024, H=16, hd=64.
typedef __attribute__((ext_vector_type(8))) __bf16 bf16x8;
typedef __attribute__((ext_vector_type(4))) float f32x4;
typedef __attribute__((ext_vector_type(4))) unsigned short u16x4;

#define LOG2E 1.4426950408889634f

__device__ __forceinline__ unsigned short f2bf(float f) {
  union { float f; unsigned int u; } x;
  x.f = f;
  unsigned int u = x.u;
  u += 0x7fffu + ((u >> 16) & 1u);   // round-to-nearest-even
  return (unsigned short)(u >> 16);
}

__device__ __forceinline__ void gload_lds16(const void* gsrc, void* lds) {
  __builtin_amdgcn_global_load_lds(
      (const __attribute__((address_space(1))) unsigned int*)gsrc,
      (__attribute__((address_space(3))) unsigned int*)lds, 16, 0, 0);
}

// ---------------------------------------------------------------------------
// 1) fp32 -> bf16 conversion for q,k,v (4096x1024 each) and 4 weights (1024^2)
// ---------------------------------------------------------------------------
__global__ __launch_bounds__(256) void cvt_all(
    const float* __restrict__ q, const float* __restrict__ k, const float* __restrict__ v,
    const float* __restrict__ w0, const float* __restrict__ w1,
    const float* __restrict__ w2, const float* __restrict__ w3,
    unsigned short* __restrict__ qb, unsigned short* __restrict__ kb,
    unsigned short* __restrict__ vb, unsigned short* __restrict__ w0b,
    unsigned short* __restrict__ w1b, unsigned short* __restrict__ w2b,
    unsigned short* __restrict__ w3b) {
  long idx = (long)blockIdx.x * 256 + threadIdx.x;     // quad index
  const long QV = 1024L * 1024;                        // quads per q/k/v
  const long WQ = 256L * 1024;                         // quads per weight
  const float* src;
  unsigned short* dst;
  long base;
  if (idx < QV)                { src = q;  dst = qb;  base = idx; }
  else if (idx < 2 * QV)       { src = k;  dst = kb;  base = idx - QV; }
  else if (idx < 3 * QV)       { src = v;  dst = vb;  base = idx - 2 * QV; }
  else if (idx < 3 * QV + WQ)  { src = w0; dst = w0b; base = idx - 3 * QV; }
  else if (idx < 3 * QV + 2*WQ){ src = w1; dst = w1b; base = idx - 3 * QV - WQ; }
  else if (idx < 3 * QV + 3*WQ){ src = w2; dst = w2b; base = idx - 3 * QV - 2 * WQ; }
  else                         { src = w3; dst = w3b; base = idx - 3 * QV - 3 * WQ; }
  f32x4 val = *(const f32x4*)(src + base * 4);
  u16x4 o;
#pragma unroll
  for (int i = 0; i < 4; ++i) o[i] = f2bf(val[i]);
  *(u16x4*)(dst + base * 4) = o;
}

// ---------------------------------------------------------------------------
// 2) bt-GEMM (m97 structure): C[M=4096][N=1024] = A[4096x1024] * W^T + bias
//    BM=BN=128, BK=32, 4 waves, 16x16x32 bf16 MFMA, global_load_lds width=16,
//    XOR-swizzled LDS (pre-swizzled global source, rule #21).
//    MODE 0: epilogue -> bf16 head layout [(b*16+h)][l][64], *oscale
//    MODE 1: epilogue -> fp32 [row][col] (final output)
// ---------------------------------------------------------------------------
template <int MODE>
__global__ __launch_bounds__(256) void gemm_bt(
    const unsigned short* A0, const unsigned short* A1, const unsigned short* A2,
    const unsigned short* W0, const unsigned short* W1, const unsigned short* W2,
    const float* b0, const float* b1, const float* b2,
    void* o0, void* o1, void* o2) {
  __shared__ char smem[32768];  // A dbuf 2x8KB @0, B dbuf 2x8KB @16KB
  const int z = blockIdx.z;
  const unsigned short* __restrict__ A = (z == 0) ? A0 : (z == 1) ? A1 : A2;
  const unsigned short* __restrict__ W = (z == 0) ? W0 : (z == 1) ? W1 : W2;
  const float* __restrict__ bias = (z == 0) ? b0 : (z == 1) ? b1 : b2;
  void* __restrict__ out = (z == 0) ? o0 : (z == 1) ? o1 : o2;
  const float oscale = (MODE == 0 && z == 0) ? 0.125f : 1.0f;  // fold 1/sqrt(64) into Q

  const int tid = threadIdx.x;
  const int lane = tid & 63;
  const int wave = tid >> 6;
  const int wm = (wave >> 1) * 64;
  const int wn = (wave & 1) * 64;
  const int bm0 = blockIdx.x * 128;
  const int bn0 = blockIdx.y * 128;
  const int K = 1024;
  const int srow = tid >> 2;   // staging row 0..63 (per half)
  const int sg = tid & 3;      // staging granule

  f32x4 acc[4][4] = {};

  auto stageA = [&](int kt, int buf) {
    char* dst = smem + buf * 8192;
#pragma unroll
    for (int h = 0; h < 2; ++h) {
      int row = srow + h * 64;
      int gs = sg ^ ((row >> 1) & 3);
      gload_lds16((const char*)(A + (long)(bm0 + row) * K + kt * 32) + gs * 16,
                  dst + h * 4096 + tid * 16);
    }
  };
  auto stageB = [&](int kt, int buf) {
    char* dst = smem + 16384 + buf * 8192;
#pragma unroll
    for (int h = 0; h < 2; ++h) {
      int row = srow + h * 64;
      int gs = sg ^ ((row >> 1) & 3);
      gload_lds16((const char*)(W + (long)(bn0 + row) * K + kt * 32) + gs * 16,
                  dst + h * 4096 + tid * 16);
    }
  };

  stageA(0, 0);
  stageB(0, 0);
  __syncthreads();

  const int nk = K / 32;
  for (int kt = 0; kt < nk; ++kt) {
    const int cur = kt & 1;
    if (kt + 1 < nk) { stageA(kt + 1, cur ^ 1); stageB(kt + 1, cur ^ 1); }
    char* curA = smem + cur * 8192;
    char* curB = smem + 16384 + cur * 8192;
    const int kb = (lane >> 4) * 16;  // this lane's k-granule byte offset
    bf16x8 af[4], bfr[4];
#pragma unroll
    for (int i = 0; i < 4; ++i) {
      int row = wm + i * 16 + (lane & 15);
      af[i] = *(const bf16x8*)(curA + row * 64 + (kb ^ (((row >> 1) & 3) << 4)));
    }
#pragma unroll
    for (int j = 0; j < 4; ++j) {
      int row = wn + j * 16 + (lane & 15);
      bfr[j] = *(const bf16x8*)(curB + row * 64 + (kb ^ (((row >> 1) & 3) << 4)));
    }
#pragma unroll
    for (int i = 0; i < 4; ++i)
#pragma unroll
      for (int j = 0; j < 4; ++j)
        acc[i][j] = __builtin_amdgcn_mfma_f32_16x16x32_bf16(af[i], bfr[j], acc[i][j], 0, 0, 0);
    __syncthreads();
  }

  // epilogue: D layout col=lane&15, row=(lane>>4)*4+reg  [m89-verified]
#pragma unroll
  for (int i = 0; i < 4; ++i) {
#pragma unroll
    for (int j = 0; j < 4; ++j) {
#pragma unroll
      for (int r = 0; r < 4; ++r) {
        int row = bm0 + wm + i * 16 + (lane >> 4) * 4 + r;
        int col = bn0 + wn + j * 16 + (lane & 15);
        float vv = (acc[i][j][r] + bias[col]) * oscale;
        if (MODE == 0) {
          int bb = row >> 11, ll = row & 2047;
          int hh = col >> 6, hd = col & 63;
          ((unsigned short*)out)[(((long)(bb * 16 + hh) * 2048 + ll) << 6) + hd] = f2bf(vv);
        } else {
          ((float*)out)[(long)row * 1024 + col] = vv;
        }
      }
    }
  }
}

// ---------------------------------------------------------------------------
// 3) V transpose: Vm[32][2048][64] -> Vt[32][64][2048]  (bf16)
// ---------------------------------------------------------------------------
__global__ __launch_bounds__(256) void transpose_v(const unsigned short* __restrict__ Vm,
                                                   unsigned short* __restrict__ Vt) {
  __shared__ unsigned short t[64][68];
  const int bh = blockIdx.y;
  const int p0 = blockIdx.x * 64;
  const int tid = threadIdx.x;
#pragma unroll
  for (int it = 0; it < 4; ++it) {
    int idx = it * 256 + tid;
    int r = idx >> 4;            // p-row 0..63
    int c4 = (idx & 15) * 4;     // hd col
    *(u16x4*)&t[r][c4] = *(const u16x4*)(Vm + ((long)bh * 2048 + p0 + r) * 64 + c4);
  }
  __syncthreads();
#pragma unroll
  for (int it = 0; it < 4; ++it) {
    int idx = it * 256 + tid;
    int hd = idx >> 4;           // 0..63
    int pp = (idx & 15) * 4;     // p offset
    u16x4 v;
#pragma unroll
    for (int j = 0; j < 4; ++j) v[j] = t[pp + j][hd];
    *(u16x4*)(Vt + ((long)bh * 64 + hd) * 2048 + p0 + pp) = v;
  }
}

// ---------------------------------------------------------------------------
// 4) Flash attention: grid (16 q-tiles, 32 bh), 256 threads (4 waves x 32 rows)
//    Q pre-scaled by 0.125 in projection. K/V staged via global_load_lds
//    (XOR-swizzled), P bounced through swizzled LDS, online softmax.
//    mask is int32 (bool -> int per harness convention).
// ---------------------------------------------------------------------------
__global__ __launch_bounds__(256) void attn_fwd(
    const unsigned short* __restrict__ Qm,  // [32][2048][64]
    const unsigned short* __restrict__ Km,  // [32][2048][64]
    const unsigned short* __restrict__ Vt,  // [32][64][2048]
    const int* __restrict__ mask,           // [2][2048] int32
    unsigned short* __restrict__ ao) {      // [2][2048][1024] bf16
  __shared__ char smem[65536];
  char* const Kl = smem;            // [128][64] bf16 (rows 128B), 16KB
  char* const Vl = smem + 16384;    // [64][128] bf16 (rows 256B), 16KB
  char* const Pl = smem + 32768;    // [128][128] bf16 (rows 256B), 32KB
  const int tid = threadIdx.x, lane = tid & 63, wave = tid >> 6;
  const int bh = blockIdx.y;
  const int b = bh >> 4, h = bh & 15;
  const int q0 = blockIdx.x * 128;
  const unsigned short* Qbase = Qm + ((long)bh * 2048 + q0) * 64;
  const unsigned short* Kbase = Km + (long)bh * 2048 * 64;
  const unsigned short* Vbase = Vt + (long)bh * 64 * 2048;

  auto stageK = [&](int pt) {
    const unsigned short* g = Kbase + (long)pt * 128 * 64;
#pragma unroll
    for (int hh = 0; hh < 4; ++hh) {
      int row = hh * 32 + (tid >> 3);
      int gs = (tid & 7) ^ (row & 7);
      gload_lds16((const char*)(g + (long)row * 64) + gs * 16, Kl + hh * 4096 + tid * 16);
    }
  };
  auto stageV = [&](int pt) {
#pragma unroll
    for (int hh = 0; hh < 4; ++hh) {
      int row = hh * 16 + (tid >> 4);
      int gs = (tid & 15) ^ (row & 7);
      gload_lds16((const char*)(Vbase + (long)row * 2048 + pt * 128) + gs * 16,
                  Vl + hh * 4096 + tid * 16);
    }
  };

  // Q fragments straight from global (one-time 16KB read per block)
  bf16x8 qf[2][2];
#pragma unroll
  for (int fm = 0; fm < 2; ++fm)
#pragma unroll
    for (int ks = 0; ks < 2; ++ks) {
      int row = wave * 32 + fm * 16 + (lane & 15);
      qf[fm][ks] = *(const bf16x8*)(Qbase + row * 64 + ks * 32 + (lane >> 4) * 8);
    }

  stageK(0);
  stageV(0);

  f32x4 o[2][4] = {};
  float mrow[2][4], lrow[2][4];
#pragma unroll
  for (int fm = 0; fm < 2; ++fm)
#pragma unroll
    for (int r = 0; r < 4; ++r) { mrow[fm][r] = -__builtin_inff(); lrow[fm][r] = 0.f; }

  __syncthreads();  // K0,V0 arrived (vmcnt drained before barrier)

  const int NT = 16;
  for (int pt = 0; pt < NT; ++pt) {
    // ---- S = Q * K^T (already scaled via Q) ----
    f32x4 sf[2][8];
#pragma unroll
    for (int fn = 0; fn < 8; ++fn) {
      int row = fn * 16 + (lane & 15);
      int sw = (row & 7) << 4;
      bf16x8 k0 = *(const bf16x8*)(Kl + row * 128 + (((lane >> 4) * 16) ^ sw));
      bf16x8 k1 = *(const bf16x8*)(Kl + row * 128 + ((64 + (lane >> 4) * 16) ^ sw));
#pragma unroll
      for (int fm = 0; fm < 2; ++fm) {
        f32x4 zz = {};
        zz = __builtin_amdgcn_mfma_f32_16x16x32_bf16(qf[fm][0], k0, zz, 0, 0, 0);
        sf[fm][fn] = __builtin_amdgcn_mfma_f32_16x16x32_bf16(qf[fm][1], k1, zz, 0, 0, 0);
      }
    }
    // ---- mask (scores <- MASK_FILL where !mask) ----
#pragma unroll
    for (int fn = 0; fn < 8; ++fn) {
      int mk = mask[b * 2048 + pt * 128 + fn * 16 + (lane & 15)];
      if (!mk) {
#pragma unroll
        for (int fm = 0; fm < 2; ++fm)
#pragma unroll
          for (int r = 0; r < 4; ++r) sf[fm][fn][r] = -1e8f;
      }
    }
    // ---- online softmax ----
    float al[2][4];
#pragma unroll
    for (int fm = 0; fm < 2; ++fm)
#pragma unroll
      for (int r = 0; r < 4; ++r) {
        float mx = sf[fm][0][r];
#pragma unroll
        for (int fn = 1; fn < 8; ++fn) mx = fmaxf(mx, sf[fm][fn][r]);
#pragma unroll
        for (int off = 1; off < 16; off <<= 1) mx = fmaxf(mx, __shfl_xor(mx, off, 64));
        float mn = fmaxf(mrow[fm][r], mx);
        al[fm][r] = exp2f((mrow[fm][r] - mn) * LOG2E);
        mrow[fm][r] = mn;
      }
    float rs[2][4] = {};
#pragma unroll
    for (int fm = 0; fm < 2; ++fm)
#pragma unroll
      for (int fn = 0; fn < 8; ++fn)
#pragma unroll
        for (int r = 0; r < 4; ++r) {
          float p = exp2f((sf[fm][fn][r] - mrow[fm][r]) * LOG2E);
          sf[fm][fn][r] = p;
          rs[fm][r] += p;
        }
#pragma unroll
    for (int fm = 0; fm < 2; ++fm)
#pragma unroll
      for (int r = 0; r < 4; ++r) {
        float s = rs[fm][r];
#pragma unroll
        for (int off = 1; off < 16; off <<= 1) s += __shfl_xor(s, off, 64);
        lrow[fm][r] = lrow[fm][r] * al[fm][r] + s;
      }
#pragma unroll
    for (int fm = 0; fm < 2; ++fm)
#pragma unroll
      for (int jn = 0; jn < 4; ++jn)
#pragma unroll
        for (int r = 0; r < 4; ++r) o[fm][jn][r] *= al[fm][r];
    // ---- write P (bf16) to swizzled LDS ----
#pragma unroll
    for (int fm = 0; fm < 2; ++fm)
#pragma unroll
      for (int fn = 0; fn < 8; ++fn)
#pragma unroll
        for (int r = 0; r < 4; ++r) {
          int row = wave * 32 + fm * 16 + (lane >> 4) * 4 + r;
          int cb = (fn * 16 + (lane & 15)) * 2;
          *(unsigned short*)(Pl + row * 256 + (cb ^ ((row & 7) << 4))) = f2bf(sf[fm][fn][r]);
        }
    __syncthreads();  // P visible; K reads done
    if (pt + 1 < NT) stageK(pt + 1);
    // ---- O += P * V ----
#pragma unroll
    for (int ks = 0; ks < 4; ++ks) {
      bf16x8 pf[2];
#pragma unroll
      for (int fm = 0; fm < 2; ++fm) {
        int prow = wave * 32 + fm * 16 + (lane & 15);
        pf[fm] = *(const bf16x8*)(Pl + prow * 256 + ((ks * 64 + (lane >> 4) * 16) ^ ((prow & 7) << 4)));
      }
#pragma unroll
      for (int jn = 0; jn < 4; ++jn) {
        int vrow = jn * 16 + (lane & 15);
        bf16x8 vf = *(const bf16x8*)(Vl + vrow * 256 + ((ks * 64 + (lane >> 4) * 16) ^ ((vrow & 7) << 4)));
#pragma unroll
        for (int fm = 0; fm < 2; ++fm)
          o[fm][jn] = __builtin_amdgcn_mfma_f32_16x16x32_bf16(pf[fm], vf, o[fm][jn], 0, 0, 0);
      }
    }
    __syncthreads();  // V reads + P reads done
    if (pt + 1 < NT) stageV(pt + 1);
  }

  // ---- epilogue: O /= l, merge heads ----
#pragma unroll
  for (int fm = 0; fm < 2; ++fm) {
    float inv[4];
#pragma unroll
    for (int r = 0; r < 4; ++r) inv[r] = 1.0f / lrow[fm][r];
#pragma unroll
    for (int jn = 0; jn < 4; ++jn)
#pragma unroll
      for (int r = 0; r < 4; ++r) {
        int qrow = q0 + wave * 32 + fm * 16 + (lane >> 4) * 4 + r;
        int hd = jn * 16 + (lane & 15);
        ao[((long)(b * 2048 + qrow) << 10) + h * 64 + hd] = f2bf(o[fm][jn][r] * inv[r]);
      }
  }
}

// ---------------------------------------------------------------------------
extern "C" void kernel_launch(void* const* d_in, const int* in_sizes, int n_in,
                              void* d_out, int out_size, void* d_ws, size_t ws_size,
                              hipStream_t stream) {
  const float* q = (const float*)d_in[0];
  const float* k = (const float*)d_in[1];
  const float* v = (const float*)d_in[2];
  const int* mask = (const int*)d_in[3];
  const float* Wq = (const float*)d_in[4];
  const float* bq = (const float*)d_in[5];
  const float* Wk = (const float*)d_in[6];
  const float* bk = (const float*)d_in[7];
  const float* Wv = (const float*)d_in[8];
  const float* bv = (const float*)d_in[9];
  const float* Wo = (const float*)d_in[10];
  const float* bo = (const float*)d_in[11];

  char* ws = (char*)d_ws;
  unsigned short* qb  = (unsigned short*)(ws + (0L << 20));   // 8MB
  unsigned short* kb  = (unsigned short*)(ws + (8L << 20));   // 8MB
  unsigned short* vb  = (unsigned short*)(ws + (16L << 20));  // 8MB
  unsigned short* wqb = (unsigned short*)(ws + (24L << 20));  // 2MB
  unsigned short* wkb = (unsigned short*)(ws + (26L << 20));  // 2MB
  unsigned short* wvb = (unsigned short*)(ws + (28L << 20));  // 2MB
  unsigned short* wob = (unsigned short*)(ws + (30L << 20));  // 2MB
  unsigned short* Qh  = (unsigned short*)(ws + (32L << 20));  // 8MB [32][2048][64]
  unsigned short* Kh  = (unsigned short*)(ws + (40L << 20));  // 8MB
  unsigned short* Vh  = (unsigned short*)(ws + (48L << 20));  // 8MB
  unsigned short* VhT = (unsigned short*)(ws + (56L << 20));  // 8MB [32][64][2048]
  unsigned short* aob = (unsigned short*)(ws + (64L << 20));  // 8MB [4096][1024]

  // 1) convert all fp32 inputs to bf16
  cvt_all<<<16384, 256, 0, stream>>>(q, k, v, Wq, Wk, Wv, Wo,
                                     qb, kb, vb, wqb, wkb, wvb, wob);
  // 2) QKV projections (z=0:Q scaled 0.125, z=1:K, z=2:V) -> head layout bf16
  gemm_bt<0><<<dim3(32, 8, 3), 256, 0, stream>>>(qb, kb, vb, wqb, wkb, wvb,
                                                 bq, bk, bv, Qh, Kh, Vh);
  // 3) transpose V to [bh][hd][P]
  transpose_v<<<dim3(32, 32), 256, 0, stream>>>(Vh, VhT);
  // 4) flash attention -> merged-head bf16 activations
  attn_fwd<<<dim3(16, 32), 256, 0, stream>>>(Qh, Kh, VhT, mask, aob);
  // 5) output projection -> fp32 d_out
  gemm_bt<1><<<dim3(32, 8, 1), 256, 0, stream>>>(aob, aob, aob, wob, wob, wob,
                                                 bo, bo, bo, d_out, d_out, d_out);
  (void)in_sizes; (void)n_in; (void)out_size; (void)ws_size;
}

// Round 3
// 162.326 us; speedup vs baseline: 1.4370x; 1.4370x over previous
//
#include <hip/hip_runtime.h>
#include <hip/hip_bf16.h>

// MHA forward, bf16-MFMA pipeline.
// Shapes: B=2, L=P=2048, D=1024, H=16, hd=64.
typedef __attribute__((ext_vector_type(8))) __bf16 bf16x8;
typedef __attribute__((ext_vector_type(4))) float f32x4;
typedef __attribute__((ext_vector_type(16))) float f32x16;
typedef __attribute__((ext_vector_type(4))) unsigned short u16x4;
typedef __attribute__((ext_vector_type(2))) unsigned int u32x2;

#define LOG2E 1.4426950408889634f

__device__ __forceinline__ unsigned short f2bf(float f) {
  union { float f; unsigned int u; } x;
  x.f = f;
  unsigned int u = x.u;
  u += 0x7fffu + ((u >> 16) & 1u);   // round-to-nearest-even
  return (unsigned short)(u >> 16);
}

__device__ __forceinline__ unsigned int cvtpk_bf16(float lo, float hi) {
  unsigned int r;
  asm("v_cvt_pk_bf16_f32 %0, %1, %2" : "=v"(r) : "v"(lo), "v"(hi));
  return r;
}

__device__ __forceinline__ void plswap(unsigned int& a, unsigned int& b) {
  auto r = __builtin_amdgcn_permlane32_swap((int)a, (int)b, false, false);
  a = (unsigned int)r[0];
  b = (unsigned int)r[1];
}

__device__ __forceinline__ void gload_lds16(const void* gsrc, void* lds) {
  __builtin_amdgcn_global_load_lds(
      (const __attribute__((address_space(1))) unsigned int*)gsrc,
      (__attribute__((address_space(3))) unsigned int*)lds, 16, 0, 0);
}

// ---------------------------------------------------------------------------
// 1) fp32 -> bf16 conversion for q,k,v (4096x1024 each) and 4 weights (1024^2)
// ---------------------------------------------------------------------------
__global__ __launch_bounds__(256) void cvt_all(
    const float* __restrict__ q, const float* __restrict__ k, const float* __restrict__ v,
    const float* __restrict__ w0, const float* __restrict__ w1,
    const float* __restrict__ w2, const float* __restrict__ w3,
    unsigned short* __restrict__ qb, unsigned short* __restrict__ kb,
    unsigned short* __restrict__ vb, unsigned short* __restrict__ w0b,
    unsigned short* __restrict__ w1b, unsigned short* __restrict__ w2b,
    unsigned short* __restrict__ w3b) {
  long idx = (long)blockIdx.x * 256 + threadIdx.x;     // quad index
  const long QV = 1024L * 1024;                        // quads per q/k/v
  const long WQ = 256L * 1024;                         // quads per weight
  const float* src;
  unsigned short* dst;
  long base;
  if (idx < QV)                { src = q;  dst = qb;  base = idx; }
  else if (idx < 2 * QV)       { src = k;  dst = kb;  base = idx - QV; }
  else if (idx < 3 * QV)       { src = v;  dst = vb;  base = idx - 2 * QV; }
  else if (idx < 3 * QV + WQ)  { src = w0; dst = w0b; base = idx - 3 * QV; }
  else if (idx < 3 * QV + 2*WQ){ src = w1; dst = w1b; base = idx - 3 * QV - WQ; }
  else if (idx < 3 * QV + 3*WQ){ src = w2; dst = w2b; base = idx - 3 * QV - 2 * WQ; }
  else                         { src = w3; dst = w3b; base = idx - 3 * QV - 3 * WQ; }
  f32x4 val = *(const f32x4*)(src + base * 4);
  u16x4 o;
#pragma unroll
  for (int i = 0; i < 4; ++i) o[i] = f2bf(val[i]);
  *(u16x4*)(dst + base * 4) = o;
}

// ---------------------------------------------------------------------------
// 2) bt-GEMM (m97 structure): C[M=4096][N=1024] = A[4096x1024] * W^T + bias
// ---------------------------------------------------------------------------
template <int MODE>
__global__ __launch_bounds__(256) void gemm_bt(
    const unsigned short* A0, const unsigned short* A1, const unsigned short* A2,
    const unsigned short* W0, const unsigned short* W1, const unsigned short* W2,
    const float* b0, const float* b1, const float* b2,
    void* o0, void* o1, void* o2) {
  __shared__ char smem[32768];  // A dbuf 2x8KB @0, B dbuf 2x8KB @16KB
  const int z = blockIdx.z;
  const unsigned short* __restrict__ A = (z == 0) ? A0 : (z == 1) ? A1 : A2;
  const unsigned short* __restrict__ W = (z == 0) ? W0 : (z == 1) ? W1 : W2;
  const float* __restrict__ bias = (z == 0) ? b0 : (z == 1) ? b1 : b2;
  void* __restrict__ out = (z == 0) ? o0 : (z == 1) ? o1 : o2;
  const float oscale = (MODE == 0 && z == 0) ? 0.125f : 1.0f;  // fold 1/sqrt(64) into Q

  const int tid = threadIdx.x;
  const int lane = tid & 63;
  const int wave = tid >> 6;
  const int wm = (wave >> 1) * 64;
  const int wn = (wave & 1) * 64;
  const int bm0 = blockIdx.x * 128;
  const int bn0 = blockIdx.y * 128;
  const int K = 1024;
  const int srow = tid >> 2;   // staging row 0..63 (per half)
  const int sg = tid & 3;      // staging granule

  f32x4 acc[4][4] = {};

  auto stageA = [&](int kt, int buf) {
    char* dst = smem + buf * 8192;
#pragma unroll
    for (int h = 0; h < 2; ++h) {
      int row = srow + h * 64;
      int gs = sg ^ ((row >> 1) & 3);
      gload_lds16((const char*)(A + (long)(bm0 + row) * K + kt * 32) + gs * 16,
                  dst + h * 4096 + tid * 16);
    }
  };
  auto stageB = [&](int kt, int buf) {
    char* dst = smem + 16384 + buf * 8192;
#pragma unroll
    for (int h = 0; h < 2; ++h) {
      int row = srow + h * 64;
      int gs = sg ^ ((row >> 1) & 3);
      gload_lds16((const char*)(W + (long)(bn0 + row) * K + kt * 32) + gs * 16,
                  dst + h * 4096 + tid * 16);
    }
  };

  stageA(0, 0);
  stageB(0, 0);
  __syncthreads();

  const int nk = K / 32;
  for (int kt = 0; kt < nk; ++kt) {
    const int cur = kt & 1;
    if (kt + 1 < nk) { stageA(kt + 1, cur ^ 1); stageB(kt + 1, cur ^ 1); }
    char* curA = smem + cur * 8192;
    char* curB = smem + 16384 + cur * 8192;
    const int kb = (lane >> 4) * 16;  // this lane's k-granule byte offset
    bf16x8 af[4], bfr[4];
#pragma unroll
    for (int i = 0; i < 4; ++i) {
      int row = wm + i * 16 + (lane & 15);
      af[i] = *(const bf16x8*)(curA + row * 64 + (kb ^ (((row >> 1) & 3) << 4)));
    }
#pragma unroll
    for (int j = 0; j < 4; ++j) {
      int row = wn + j * 16 + (lane & 15);
      bfr[j] = *(const bf16x8*)(curB + row * 64 + (kb ^ (((row >> 1) & 3) << 4)));
    }
#pragma unroll
    for (int i = 0; i < 4; ++i)
#pragma unroll
      for (int j = 0; j < 4; ++j)
        acc[i][j] = __builtin_amdgcn_mfma_f32_16x16x32_bf16(af[i], bfr[j], acc[i][j], 0, 0, 0);
    __syncthreads();
  }

  // epilogue: D layout col=lane&15, row=(lane>>4)*4+reg  [m89-verified]
#pragma unroll
  for (int i = 0; i < 4; ++i) {
#pragma unroll
    for (int j = 0; j < 4; ++j) {
#pragma unroll
      for (int r = 0; r < 4; ++r) {
        int row = bm0 + wm + i * 16 + (lane >> 4) * 4 + r;
        int col = bn0 + wn + j * 16 + (lane & 15);
        float vv = (acc[i][j][r] + bias[col]) * oscale;
        if (MODE == 0) {
          int bb = row >> 11, ll = row & 2047;
          int hh = col >> 6, hd = col & 63;
          ((unsigned short*)out)[(((long)(bb * 16 + hh) * 2048 + ll) << 6) + hd] = f2bf(vv);
        } else {
          ((float*)out)[(long)row * 1024 + col] = vv;
        }
      }
    }
  }
}

// ---------------------------------------------------------------------------
// 3) V transpose: Vm[32][2048][64] -> Vt[32][64][2048]  (bf16)
// ---------------------------------------------------------------------------
__global__ __launch_bounds__(256) void transpose_v(const unsigned short* __restrict__ Vm,
                                                   unsigned short* __restrict__ Vt) {
  __shared__ unsigned short t[64][68];
  const int bh = blockIdx.y;
  const int p0 = blockIdx.x * 64;
  const int tid = threadIdx.x;
#pragma unroll
  for (int it = 0; it < 4; ++it) {
    int idx = it * 256 + tid;
    int r = idx >> 4;            // p-row 0..63
    int c4 = (idx & 15) * 4;     // hd col
    *(u16x4*)&t[r][c4] = *(const u16x4*)(Vm + ((long)bh * 2048 + p0 + r) * 64 + c4);
  }
  __syncthreads();
#pragma unroll
  for (int it = 0; it < 4; ++it) {
    int idx = it * 256 + tid;
    int hd = idx >> 4;           // 0..63
    int pp = (idx & 15) * 4;     // p offset
    u16x4 v;
#pragma unroll
    for (int j = 0; j < 4; ++j) v[j] = t[pp + j][hd];
    *(u16x4*)(Vt + ((long)bh * 64 + hd) * 2048 + p0 + pp) = v;
  }
}

// ---------------------------------------------------------------------------
// 4) Flash attention v2 (swapped-operand, in-register softmax).
//    grid (16 q-tiles of 128, 32 bh), 256 threads = 4 waves x 32 q-rows.
//    S^T = mfma32x32x16(K, Q^T): lane holds col q=lane&31, rows p per reg
//      (p = (reg&3)+8*(reg>>2)+4*(lane>>5), psub adds 32).
//    O^T = mfma32x32x16(V^T, P^T): lane holds col q, rows d per reg.
//    P fragment built in-register: v_cvt_pk_bf16_f32 + permlane32_swap.
//    K LDS [64p][64hd], V LDS [64d][64p], XOR-swizzled granules, dbuf.
// ---------------------------------------------------------------------------
__global__ __launch_bounds__(256) void attn_fwd(
    const unsigned short* __restrict__ Qm,  // [32][2048][64]
    const unsigned short* __restrict__ Km,  // [32][2048][64]
    const unsigned short* __restrict__ Vt,  // [32][64][2048]
    const int* __restrict__ mask,           // [2][2048] int32
    unsigned short* __restrict__ ao) {      // [2][2048][1024] bf16
  __shared__ char smem[41088];
  char* const Kl = smem;                        // dbuf 2 x [64 rows][128B]
  char* const Vl = smem + 16384;                // dbuf 2 x [64 rows][128B]
  float* const maskb = (float*)(smem + 32768);  // [2048] f32 bias (0 / -1e8)
  int* const allm = (int*)(smem + 40960);       // [32] per-tile all-ones flag

  const int tid = threadIdx.x, lane = tid & 63, wave = tid >> 6;
  const int h2 = lane >> 5;     // half index (0/1)
  const int ql = lane & 31;     // this lane's q within the wave tile
  const int bh = blockIdx.y, b = bh >> 4, hh = bh & 15;
  const int q0 = blockIdx.x * 128;
  const unsigned short* Qbase = Qm + ((long)bh * 2048 + q0 + wave * 32) * 64;
  const unsigned short* Kbase = Km + (long)bh * 2048 * 64;
  const unsigned short* Vbase = Vt + (long)bh * 64 * 2048;

  // ---- mask bias + per-tile all-ones ballot flags (one-time) ----
  {
    const int* mrow = mask + b * 2048;
    int p8 = tid * 8;
    int ok = 1;
#pragma unroll
    for (int i = 0; i < 8; ++i) {
      int mv = mrow[p8 + i];
      ok &= (mv != 0);
      maskb[p8 + i] = mv ? 0.f : -1.0e8f;
    }
    unsigned long long bal = __ballot(ok != 0);
    if (lane < 8) allm[wave * 8 + lane] = (int)(((bal >> (lane * 8)) & 0xFFull) == 0xFFull);
  }

  auto stageK = [&](int pt, int buf) {
    char* dst = Kl + buf * 8192;
#pragma unroll
    for (int c = 0; c < 2; ++c) {
      int G = c * 256 + tid;
      int r = G >> 3, g = G & 7;
      gload_lds16((const char*)(Kbase + (long)(pt * 64 + r) * 64) + ((g ^ (r & 7)) << 4),
                  dst + G * 16);
    }
  };
  auto stageV = [&](int pt, int buf) {
    char* dst = Vl + buf * 8192;
#pragma unroll
    for (int c = 0; c < 2; ++c) {
      int G = c * 256 + tid;
      int r = G >> 3, g = G & 7;
      gload_lds16((const char*)(Vbase + (long)r * 2048 + pt * 64) + ((g ^ (r & 7)) << 4),
                  dst + G * 16);
    }
  };

  // Q fragments, held in registers for the whole kernel (B-operand layout:
  // lane holds col q=ql, k = ks*16 + h2*8 + j)
  bf16x8 qf[4];
#pragma unroll
  for (int ks = 0; ks < 4; ++ks)
    qf[ks] = *(const bf16x8*)(Qbase + (long)ql * 64 + ks * 16 + h2 * 8);

  stageK(0, 0);
  stageV(0, 0);

  f32x16 o0 = {}, o1 = {};                 // O^T accs: d-tiles 0-31 / 32-63
  float ml = -3.0e38f, lsum = 0.f;         // running max (log2 domain), denom
  __syncthreads();

  const int NT = 32;
  for (int pt = 0; pt < NT; ++pt) {
    const int cur = pt & 1;
    if (pt + 1 < NT) { stageK(pt + 1, cur ^ 1); stageV(pt + 1, cur ^ 1); }
    const char* Kc = Kl + cur * 8192;
    const char* Vc = Vl + cur * 8192;

    // ---- S^T = K * Q^T : two 32p x 32q sub-tiles ----
    f32x16 s0 = {}, s1 = {};
#pragma unroll
    for (int ks = 0; ks < 4; ++ks) {
      int gl = ks * 2 + h2;
      int r0 = ql, r1 = 32 + ql;
      bf16x8 k0 = *(const bf16x8*)(Kc + r0 * 128 + ((gl ^ (r0 & 7)) << 4));
      bf16x8 k1 = *(const bf16x8*)(Kc + r1 * 128 + ((gl ^ (r1 & 7)) << 4));
      s0 = __builtin_amdgcn_mfma_f32_32x32x16_bf16(k0, qf[ks], s0, 0, 0, 0);
      s1 = __builtin_amdgcn_mfma_f32_32x32x16_bf16(k1, qf[ks], s1, 0, 0, 0);
    }

    // ---- mask (exact where-semantics; skipped when tile all-ones) ----
    if (!allm[pt]) {
#pragma unroll
      for (int rq = 0; rq < 4; ++rq) {
        f32x4 m0 = *(const f32x4*)&maskb[pt * 64 + rq * 8 + 4 * h2];
        f32x4 m1 = *(const f32x4*)&maskb[pt * 64 + 32 + rq * 8 + 4 * h2];
#pragma unroll
        for (int i = 0; i < 4; ++i) {
          s0[rq * 4 + i] = (m0[i] != 0.f) ? -1.0e8f : s0[rq * 4 + i];
          s1[rq * 4 + i] = (m1[i] != 0.f) ? -1.0e8f : s1[rq * 4 + i];
        }
      }
    }

    // ---- online softmax (all state per-lane; q = ql) ----
    float pm = s0[0];
#pragma unroll
    for (int i = 1; i < 16; ++i) pm = fmaxf(pm, s0[i]);
#pragma unroll
    for (int i = 0; i < 16; ++i) pm = fmaxf(pm, s1[i]);
    pm = fmaxf(pm, __shfl_xor(pm, 32));
    float pml = pm * LOG2E;
    float mnl = fmaxf(ml, pml);
    float al = exp2f(ml - mnl);
    ml = mnl;
    float rs = 0.f;
#pragma unroll
    for (int i = 0; i < 16; ++i) {
      float p = exp2f(__builtin_fmaf(s0[i], LOG2E, -mnl));
      s0[i] = p; rs += p;
    }
#pragma unroll
    for (int i = 0; i < 16; ++i) {
      float p = exp2f(__builtin_fmaf(s1[i], LOG2E, -mnl));
      s1[i] = p; rs += p;
    }
    rs += __shfl_xor(rs, 32);
    lsum = lsum * al + rs;
#pragma unroll
    for (int i = 0; i < 16; ++i) { o0[i] *= al; o1[i] *= al; }

    // ---- P -> bf16 fragments in-register (cvt_pk + permlane32_swap) ----
    bf16x8 pa[4];
    {
      union { unsigned int w[4]; bf16x8 v; } u;
      unsigned int w0, w1, w2, w3;
      w0 = cvtpk_bf16(s0[0],  s0[1]);  w1 = cvtpk_bf16(s0[2],  s0[3]);
      w2 = cvtpk_bf16(s0[4],  s0[5]);  w3 = cvtpk_bf16(s0[6],  s0[7]);
      plswap(w0, w2); plswap(w1, w3);
      u.w[0] = w0; u.w[1] = w1; u.w[2] = w2; u.w[3] = w3; pa[0] = u.v;
      w0 = cvtpk_bf16(s0[8],  s0[9]);  w1 = cvtpk_bf16(s0[10], s0[11]);
      w2 = cvtpk_bf16(s0[12], s0[13]); w3 = cvtpk_bf16(s0[14], s0[15]);
      plswap(w0, w2); plswap(w1, w3);
      u.w[0] = w0; u.w[1] = w1; u.w[2] = w2; u.w[3] = w3; pa[1] = u.v;
      w0 = cvtpk_bf16(s1[0],  s1[1]);  w1 = cvtpk_bf16(s1[2],  s1[3]);
      w2 = cvtpk_bf16(s1[4],  s1[5]);  w3 = cvtpk_bf16(s1[6],  s1[7]);
      plswap(w0, w2); plswap(w1, w3);
      u.w[0] = w0; u.w[1] = w1; u.w[2] = w2; u.w[3] = w3; pa[2] = u.v;
      w0 = cvtpk_bf16(s1[8],  s1[9]);  w1 = cvtpk_bf16(s1[10], s1[11]);
      w2 = cvtpk_bf16(s1[12], s1[13]); w3 = cvtpk_bf16(s1[14], s1[15]);
      plswap(w0, w2); plswap(w1, w3);
      u.w[0] = w0; u.w[1] = w1; u.w[2] = w2; u.w[3] = w3; pa[3] = u.v;
    }

    // ---- O^T += V^T * P^T ----
#pragma unroll
    for (int kb = 0; kb < 4; ++kb) {
      int gl = kb * 2 + h2;
      int r0 = ql, r1 = 32 + ql;
      bf16x8 v0 = *(const bf16x8*)(Vc + r0 * 128 + ((gl ^ (r0 & 7)) << 4));
      bf16x8 v1 = *(const bf16x8*)(Vc + r1 * 128 + ((gl ^ (r1 & 7)) << 4));
      o0 = __builtin_amdgcn_mfma_f32_32x32x16_bf16(v0, pa[kb], o0, 0, 0, 0);
      o1 = __builtin_amdgcn_mfma_f32_32x32x16_bf16(v1, pa[kb], o1, 0, 0, 0);
    }
    __syncthreads();
  }

  // ---- epilogue: O^T/l -> ao[b][q][h*64+d]  (d = dt*32+rq*8+4*h2+i) ----
  float inv = 1.0f / lsum;
  unsigned short* aop = ao + ((long)(b * 2048 + q0 + wave * 32 + ql) << 10) + hh * 64;
#pragma unroll
  for (int rq = 0; rq < 4; ++rq) {
    unsigned int lo = cvtpk_bf16(o0[rq * 4 + 0] * inv, o0[rq * 4 + 1] * inv);
    unsigned int hi = cvtpk_bf16(o0[rq * 4 + 2] * inv, o0[rq * 4 + 3] * inv);
    u32x2 st = {lo, hi};
    *(u32x2*)(aop + rq * 8 + 4 * h2) = st;
  }
#pragma unroll
  for (int rq = 0; rq < 4; ++rq) {
    unsigned int lo = cvtpk_bf16(o1[rq * 4 + 0] * inv, o1[rq * 4 + 1] * inv);
    unsigned int hi = cvtpk_bf16(o1[rq * 4 + 2] * inv, o1[rq * 4 + 3] * inv);
    u32x2 st = {lo, hi};
    *(u32x2*)(aop + 32 + rq * 8 + 4 * h2) = st;
  }
}

// ---------------------------------------------------------------------------
extern "C" void kernel_launch(void* const* d_in, const int* in_sizes, int n_in,
                              void* d_out, int out_size, void* d_ws, size_t ws_size,
                              hipStream_t stream) {
  const float* q = (const float*)d_in[0];
  const float* k = (const float*)d_in[1];
  const float* v = (const float*)d_in[2];
  const int* mask = (const int*)d_in[3];
  const float* Wq = (const float*)d_in[4];
  const float* bq = (const float*)d_in[5];
  const float* Wk = (const float*)d_in[6];
  const float* bk = (const float*)d_in[7];
  const float* Wv = (const float*)d_in[8];
  const float* bv = (const float*)d_in[9];
  const float* Wo = (const float*)d_in[10];
  const float* bo = (const float*)d_in[11];

  char* ws = (char*)d_ws;
  unsigned short* qb  = (unsigned short*)(ws + (0L << 20));   // 8MB
  unsigned short* kb  = (unsigned short*)(ws + (8L << 20));   // 8MB
  unsigned short* vb  = (unsigned short*)(ws + (16L << 20));  // 8MB
  unsigned short* wqb = (unsigned short*)(ws + (24L << 20));  // 2MB
  unsigned short* wkb = (unsigned short*)(ws + (26L << 20));  // 2MB
  unsigned short* wvb = (unsigned short*)(ws + (28L << 20));  // 2MB
  unsigned short* wob = (unsigned short*)(ws + (30L << 20));  // 2MB
  unsigned short* Qh  = (unsigned short*)(ws + (32L << 20));  // 8MB [32][2048][64]
  unsigned short* Kh  = (unsigned short*)(ws + (40L << 20));  // 8MB
  unsigned short* Vh  = (unsigned short*)(ws + (48L << 20));  // 8MB
  unsigned short* VhT = (unsigned short*)(ws + (56L << 20));  // 8MB [32][64][2048]
  unsigned short* aob = (unsigned short*)(ws + (64L << 20));  // 8MB [4096][1024]

  // 1) convert all fp32 inputs to bf16
  cvt_all<<<16384, 256, 0, stream>>>(q, k, v, Wq, Wk, Wv, Wo,
                                     qb, kb, vb, wqb, wkb, wvb, wob);
  // 2) QKV projections (z=0:Q scaled 0.125, z=1:K, z=2:V) -> head layout bf16
  gemm_bt<0><<<dim3(32, 8, 3), 256, 0, stream>>>(qb, kb, vb, wqb, wkb, wvb,
                                                 bq, bk, bv, Qh, Kh, Vh);
  // 3) transpose V to [bh][hd][P]
  transpose_v<<<dim3(32, 32), 256, 0, stream>>>(Vh, VhT);
  // 4) flash attention -> merged-head bf16 activations
  attn_fwd<<<dim3(16, 32), 256, 0, stream>>>(Qh, Kh, VhT, mask, aob);
  // 5) output projection -> fp32 d_out
  gemm_bt<1><<<dim3(32, 8, 1), 256, 0, stream>>>(aob, aob, aob, wob, wob, wob,
                                                 bo, bo, bo, d_out, d_out, d_out);
  (void)in_sizes; (void)n_in; (void)out_size; (void)ws_size;
}